// Round 7
// baseline (1145.744 us; speedup 1.0000x reference)
//
#include <hip/hip_runtime.h>

// x:   (2,4,8,8,8,96,96) fp32   strides: b 18874368, ci 4718592, cd 589824, t 73728, d 9216, h 96, w 1
// W:   (9,4,4,3,3,3)     fp32
// b:   (9,4)             fp32
// out: (2,4,6,6,8,96,96) fp32
//
// Round-7: d-PAIRING. Each block computes TWO adjacent d output planes
// (d0, d0+1) from one staged tile of 4 input d-planes (d0-1..d0+2).
// Evidence trail: r6 falsified LDS-pipe-bound (2x fewer read instrs ->
// flat); corrected model: VALU-issue (1296 FMA + ~590 overhead cyc per
// wave-iter) / 65% busy == 586us. d-pairing cuts staging+reads per output
// by 33%, halves barriers/loop overhead per output, and doubles the
// compute-phase length relative to per-iter stalls -> busy fraction up.
// Kept: stride-106 b64 reads, zero-once halos, goff<0 validity encoding,
// short-live-range staging, weights from workspace (wave-uniform s_load),
// (256,4) launch bounds. Grid 3456 -> 1728 (72 slabs x 4 dpairs x 6 ht).

#define BLOCK 256
#define XSTRIDE 106

__global__ void prep_kernel(const float* __restrict__ Wg,
                            const float* __restrict__ bg,
                            float* __restrict__ ws)
{
    int k = blockIdx.x * blockDim.x + threadIdx.x;
    if (k < 3888) {
        int o  = k & 3;  int r = k >> 2;
        int kw = r % 3;  r /= 3;
        int kh = r % 3;  r /= 3;
        int kd = r % 3;  r /= 3;
        int ij = r % 9;  int ci = r / 9;
        ws[k] = Wg[ij*432 + o*108 + ci*27 + kd*9 + kh*3 + kw];
    }
    if (k < 4) {
        float s = 0.f;
        #pragma unroll
        for (int ij = 0; ij < 9; ++ij) s += bg[ij*4 + k];
        ws[3888 + k] = s * (1.0f / 9.0f);
    }
}

__global__ __launch_bounds__(256, 4) void conv5d_kernel(
    const float* __restrict__ xg,
    const float* __restrict__ wsW,
    float* __restrict__ outg)
{
    __shared__ float xs[72 * XSTRIDE];   // 4 planes x 18 hr x 106 = 30528 B

    // zero once: w-halo cols (idx 4 / 101) and out-of-range d/h rows are
    // never re-staged afterwards.
    for (int k = threadIdx.x; k < 72 * XSTRIDE; k += BLOCK) xs[k] = 0.f;

    // XCD-aware block decode: 1728 blocks = 72 (b,c,t) slabs x 4 dpairs x 6 ht.
    int bi   = blockIdx.x;
    int xcd  = bi & 7;
    int g    = bi >> 3;              // 0..215
    int slab = xcd*9 + g/24;         // 0..71
    int r2   = g % 24;
    int dp   = r2 / 6;               // 0..3
    int ht   = r2 % 6;               // 0..5
    int b    = slab / 36;
    int ct   = slab % 36;
    int c    = ct / 6;
    int t    = ct % 6;
    int h0   = ht * 16;
    int d0   = dp * 2;               // output planes d0, d0+1

    int wt     = threadIdx.x & 15;   // w0 = 6*wt
    int hr_out = threadIdx.x >> 4;   // 0..15

    // ---- loop-invariant staging descriptors (7 passes, valid u < 1728) ----
    int goff[7];   // <0 => invalid (halo/out-of-range), skip
    int lw[7];
    #pragma unroll
    for (int p = 0; p < 7; ++p) {
        int u   = threadIdx.x + p*BLOCK;   // 0..1791
        int row = u / 24;                  // 0..74 (masked below)
        int q   = u % 24;
        int pl  = row / 18;                // 0..3
        int hr  = row % 18;
        int dd  = d0 + pl - 1;             // d0-1 .. d0+2
        int hh  = h0 + hr - 1;
        bool ok = (u < 1728) && ((unsigned)dd < 8u) && ((unsigned)hh < 96u);
        goff[p] = ok ? (dd*9216 + hh*96 + q*4) : -1;
        lw[p]   = row*XSTRIDE + 5 + q*4;   // w=0 at idx 5
    }

    float acc[2][4][6] = {};

    #pragma unroll 1
    for (int it = 0; it < 36; ++it) {
        int ci = it / 9;
        int ij = it % 9;
        int i  = ij / 3;
        int j  = ij % 3;
        const float* xp = xg + (size_t)b*18874368 + (size_t)ci*4718592
                             + (size_t)(c + i)*589824
                             + (size_t)(t + j)*73728;

        __syncthreads();   // previous iter's readers done before overwrite

        // ---- stage: 7 global loads -> LDS (short live range) ----
        float4 v[7];
        #pragma unroll
        for (int p = 0; p < 7; ++p)
            if (goff[p] >= 0) v[p] = *(const float4*)(xp + goff[p]);
        #pragma unroll
        for (int p = 0; p < 7; ++p) {
            if (goff[p] >= 0) {
                xs[lw[p] + 0] = v[p].x;
                xs[lw[p] + 1] = v[p].y;
                xs[lw[p] + 2] = v[p].z;
                xs[lw[p] + 3] = v[p].w;
            }
        }
        __syncthreads();

        // ---- compute: 4 planes x 3 kh; each read row feeds 1-2 outputs ----
        // 1296 FMAs/thread/iter (648 per output plane)
        const float4* wq4 = (const float4*)(wsW + (ci*9 + ij)*108);
        #pragma unroll
        for (int pl4 = 0; pl4 < 4; ++pl4) {
            #pragma unroll
            for (int kh = 0; kh < 3; ++kh) {
                const float2* xr2 = (const float2*)
                    &xs[(pl4*18 + hr_out + kh)*XSTRIDE + 4 + 6*wt];
                float2 p0 = xr2[0], p1 = xr2[1], p2 = xr2[2], p3 = xr2[3];
                float xv[8] = {p0.x, p0.y, p1.x, p1.y, p2.x, p2.y, p3.x, p3.y};
                #pragma unroll
                for (int s = 0; s < 2; ++s) {
                    int rel = pl4 - s;           // weight kd index for output s
                    if (rel < 0 || rel > 2) continue;   // resolved at compile time
                    const float4* wr = wq4 + (rel*3 + kh)*3;
                    float4 wk0 = wr[0];
                    float4 wk1 = wr[1];
                    float4 wk2 = wr[2];
                    #pragma unroll
                    for (int vv = 0; vv < 6; ++vv) {
                        float a = xv[vv], bb = xv[vv+1], cc = xv[vv+2];
                        acc[s][0][vv] = fmaf(a,  wk0.x, acc[s][0][vv]);
                        acc[s][1][vv] = fmaf(a,  wk0.y, acc[s][1][vv]);
                        acc[s][2][vv] = fmaf(a,  wk0.z, acc[s][2][vv]);
                        acc[s][3][vv] = fmaf(a,  wk0.w, acc[s][3][vv]);
                        acc[s][0][vv] = fmaf(bb, wk1.x, acc[s][0][vv]);
                        acc[s][1][vv] = fmaf(bb, wk1.y, acc[s][1][vv]);
                        acc[s][2][vv] = fmaf(bb, wk1.z, acc[s][2][vv]);
                        acc[s][3][vv] = fmaf(bb, wk1.w, acc[s][3][vv]);
                        acc[s][0][vv] = fmaf(cc, wk2.x, acc[s][0][vv]);
                        acc[s][1][vv] = fmaf(cc, wk2.y, acc[s][1][vv]);
                        acc[s][2][vv] = fmaf(cc, wk2.z, acc[s][2][vv]);
                        acc[s][3][vv] = fmaf(cc, wk2.w, acc[s][3][vv]);
                    }
                }
            }
        }
    }

    float4 mb4 = *(const float4*)(wsW + 3888);
    float mb[4] = {mb4.x, mb4.y, mb4.z, mb4.w};

    const float inv9 = 1.0f / 9.0f;
    #pragma unroll
    for (int s = 0; s < 2; ++s) {
        size_t obase = (size_t)b*10616832 + (size_t)c*442368 + (size_t)t*73728
                     + (size_t)(d0 + s)*9216 + (size_t)(h0 + hr_out)*96 + 6*wt;
        #pragma unroll
        for (int o = 0; o < 4; ++o) {
            float* op = outg + obase + (size_t)o*2654208;
            #pragma unroll
            for (int vv = 0; vv < 3; ++vv) {
                float2 st;
                st.x = acc[s][o][2*vv]   * inv9 + mb[o];
                st.y = acc[s][o][2*vv+1] * inv9 + mb[o];
                *(float2*)(op + 2*vv) = st;
            }
        }
    }
}

extern "C" void kernel_launch(void* const* d_in, const int* in_sizes, int n_in,
                              void* d_out, int out_size, void* d_ws, size_t ws_size,
                              hipStream_t stream) {
    const float* x = (const float*)d_in[0];
    const float* W = (const float*)d_in[1];
    const float* b = (const float*)d_in[2];
    float* out = (float*)d_out;
    float* ws  = (float*)d_ws;

    prep_kernel<<<16, BLOCK, 0, stream>>>(W, b, ws);
    conv5d_kernel<<<1728, BLOCK, 0, stream>>>(x, ws, out);
}

// Round 8
// 665.537 us; speedup vs baseline: 1.7215x; 1.7215x over previous
//
#include <hip/hip_runtime.h>

// x:   (2,4,8,8,8,96,96) fp32   strides: b 18874368, ci 4718592, cd 589824, t 73728, d 9216, h 96, w 1
// W:   (9,4,4,3,3,3)     fp32
// b:   (9,4)             fp32
// out: (2,4,6,6,8,96,96) fp32
//
// Round-8: r7's d-pairing with the register hog removed. r7 passed and cut
// ideal FETCH as predicted but spilled (compiler collapses to 64 VGPR +
// scratch when pressure >128; seen in r1/r5/r7). Biggest hog was the
// batched v[7] staging array (28 regs). This round: per-pass load->write
// (scheduler batches as pressure allows). Peak est ~110 < 128 cap.
// Keeps: two d output planes per block from 4 staged input planes
// (stage/read instrs -33% per output, barriers -50% per output),
// stride-106 b64 compute reads, zero-once halos, goff<0 validity,
// weights from workspace (wave-uniform), (256,4), XCD swizzle.

#define BLOCK 256
#define XSTRIDE 106

__global__ void prep_kernel(const float* __restrict__ Wg,
                            const float* __restrict__ bg,
                            float* __restrict__ ws)
{
    int k = blockIdx.x * blockDim.x + threadIdx.x;
    if (k < 3888) {
        int o  = k & 3;  int r = k >> 2;
        int kw = r % 3;  r /= 3;
        int kh = r % 3;  r /= 3;
        int kd = r % 3;  r /= 3;
        int ij = r % 9;  int ci = r / 9;
        ws[k] = Wg[ij*432 + o*108 + ci*27 + kd*9 + kh*3 + kw];
    }
    if (k < 4) {
        float s = 0.f;
        #pragma unroll
        for (int ij = 0; ij < 9; ++ij) s += bg[ij*4 + k];
        ws[3888 + k] = s * (1.0f / 9.0f);
    }
}

__global__ __launch_bounds__(256, 4) void conv5d_kernel(
    const float* __restrict__ xg,
    const float* __restrict__ wsW,
    float* __restrict__ outg)
{
    __shared__ float xs[72 * XSTRIDE];   // 4 planes x 18 hr x 106 = 30528 B

    // zero once: w-halo cols (idx 4 / 101) and out-of-range d/h rows are
    // never re-staged afterwards.
    for (int k = threadIdx.x; k < 72 * XSTRIDE; k += BLOCK) xs[k] = 0.f;

    // XCD-aware block decode: 1728 blocks = 72 (b,c,t) slabs x 4 dpairs x 6 ht.
    int bi   = blockIdx.x;
    int xcd  = bi & 7;
    int g    = bi >> 3;              // 0..215
    int slab = xcd*9 + g/24;         // 0..71
    int r2   = g % 24;
    int dp   = r2 / 6;               // 0..3
    int ht   = r2 % 6;               // 0..5
    int b    = slab / 36;
    int ct   = slab % 36;
    int c    = ct / 6;
    int t    = ct % 6;
    int h0   = ht * 16;
    int d0   = dp * 2;               // output planes d0, d0+1

    int wt     = threadIdx.x & 15;   // w0 = 6*wt
    int hr_out = threadIdx.x >> 4;   // 0..15

    // ---- loop-invariant staging descriptors (7 passes, valid u < 1728) ----
    int goff[7];   // <0 => invalid (halo/out-of-range), skip
    int lw[7];
    #pragma unroll
    for (int p = 0; p < 7; ++p) {
        int u   = threadIdx.x + p*BLOCK;   // 0..1791
        int row = u / 24;                  // 0..74
        int q   = u % 24;
        int pl  = row / 18;                // 0..3
        int hr  = row % 18;
        int dd  = d0 + pl - 1;             // d0-1 .. d0+2
        int hh  = h0 + hr - 1;
        bool ok = (u < 1728) && ((unsigned)dd < 8u) && ((unsigned)hh < 96u);
        goff[p] = ok ? (dd*9216 + hh*96 + q*4) : -1;
        lw[p]   = row*XSTRIDE + 5 + q*4;   // w=0 at idx 5
    }

    float acc[2][4][6] = {};

    #pragma unroll 1
    for (int it = 0; it < 36; ++it) {
        int ci = it / 9;
        int ij = it % 9;
        int i  = ij / 3;
        int j  = ij % 3;
        const float* xp = xg + (size_t)b*18874368 + (size_t)ci*4718592
                             + (size_t)(c + i)*589824
                             + (size_t)(t + j)*73728;

        __syncthreads();   // previous iter's readers done before overwrite

        // ---- stage: per-pass load->write (low live-reg pressure; the
        // ---- scheduler batches loads up to the VGPR cap on its own) ----
        #pragma unroll
        for (int p = 0; p < 7; ++p) {
            if (goff[p] >= 0) {
                float4 v = *(const float4*)(xp + goff[p]);
                xs[lw[p] + 0] = v.x;
                xs[lw[p] + 1] = v.y;
                xs[lw[p] + 2] = v.z;
                xs[lw[p] + 3] = v.w;
            }
        }
        __syncthreads();

        // ---- compute: 4 planes x 3 kh; interior planes feed both outputs ----
        // 1296 FMAs/thread/iter (648 per output plane)
        const float4* wq4 = (const float4*)(wsW + (ci*9 + ij)*108);
        #pragma unroll
        for (int pl4 = 0; pl4 < 4; ++pl4) {
            #pragma unroll
            for (int kh = 0; kh < 3; ++kh) {
                const float2* xr2 = (const float2*)
                    &xs[(pl4*18 + hr_out + kh)*XSTRIDE + 4 + 6*wt];
                float2 p0 = xr2[0], p1 = xr2[1], p2 = xr2[2], p3 = xr2[3];
                float xv[8] = {p0.x, p0.y, p1.x, p1.y, p2.x, p2.y, p3.x, p3.y};
                #pragma unroll
                for (int s = 0; s < 2; ++s) {
                    int rel = pl4 - s;                 // weight kd for output s
                    if (rel < 0 || rel > 2) continue;  // compile-time resolved
                    const float4* wr = wq4 + (rel*3 + kh)*3;
                    float4 wk0 = wr[0];
                    float4 wk1 = wr[1];
                    float4 wk2 = wr[2];
                    #pragma unroll
                    for (int vv = 0; vv < 6; ++vv) {
                        float a = xv[vv], bb = xv[vv+1], cc = xv[vv+2];
                        acc[s][0][vv] = fmaf(a,  wk0.x, acc[s][0][vv]);
                        acc[s][1][vv] = fmaf(a,  wk0.y, acc[s][1][vv]);
                        acc[s][2][vv] = fmaf(a,  wk0.z, acc[s][2][vv]);
                        acc[s][3][vv] = fmaf(a,  wk0.w, acc[s][3][vv]);
                        acc[s][0][vv] = fmaf(bb, wk1.x, acc[s][0][vv]);
                        acc[s][1][vv] = fmaf(bb, wk1.y, acc[s][1][vv]);
                        acc[s][2][vv] = fmaf(bb, wk1.z, acc[s][2][vv]);
                        acc[s][3][vv] = fmaf(bb, wk1.w, acc[s][3][vv]);
                        acc[s][0][vv] = fmaf(cc, wk2.x, acc[s][0][vv]);
                        acc[s][1][vv] = fmaf(cc, wk2.y, acc[s][1][vv]);
                        acc[s][2][vv] = fmaf(cc, wk2.z, acc[s][2][vv]);
                        acc[s][3][vv] = fmaf(cc, wk2.w, acc[s][3][vv]);
                    }
                }
            }
        }
    }

    float4 mb4 = *(const float4*)(wsW + 3888);
    float mb[4] = {mb4.x, mb4.y, mb4.z, mb4.w};

    const float inv9 = 1.0f / 9.0f;
    #pragma unroll
    for (int s = 0; s < 2; ++s) {
        size_t obase = (size_t)b*10616832 + (size_t)c*442368 + (size_t)t*73728
                     + (size_t)(d0 + s)*9216 + (size_t)(h0 + hr_out)*96 + 6*wt;
        #pragma unroll
        for (int o = 0; o < 4; ++o) {
            float* op = outg + obase + (size_t)o*2654208;
            #pragma unroll
            for (int vv = 0; vv < 3; ++vv) {
                float2 st;
                st.x = acc[s][o][2*vv]   * inv9 + mb[o];
                st.y = acc[s][o][2*vv+1] * inv9 + mb[o];
                *(float2*)(op + 2*vv) = st;
            }
        }
    }
}

extern "C" void kernel_launch(void* const* d_in, const int* in_sizes, int n_in,
                              void* d_out, int out_size, void* d_ws, size_t ws_size,
                              hipStream_t stream) {
    const float* x = (const float*)d_in[0];
    const float* W = (const float*)d_in[1];
    const float* b = (const float*)d_in[2];
    float* out = (float*)d_out;
    float* ws  = (float*)d_ws;

    prep_kernel<<<16, BLOCK, 0, stream>>>(W, b, ws);
    conv5d_kernel<<<1728, BLOCK, 0, stream>>>(x, ws, out);
}